// Round 14
// baseline (232.315 us; speedup 1.0000x reference)
//
#include <hip/hip_runtime.h>

// Performer (FAVOR+) attention, MI355X.
// B=4 N=4096 H=16 D=64 DIM=1024 M=256.
// Pipeline (5 launches):
//  k_wtrans:  z0-2: W f32 -> wt[g][n][k] fp16; z3: omega->fp16; z4-11: x->xh fp16
//  k_gemm:    256x256, BK=32, ring-4 LDS, DEPTH-3 prefetch (r14): stage
//             A/B(t+3) after entry barrier into buf (t-1)&3 (WAR-safe: all
//             waves' t-1 reads lgkm-complete before barrier); entry vmcnt(8)
//             keeps 8 loads in flight, ~3 iters (~1300cyc) latency cover.
//             Q,K -> qkv fp16 (stride 2048); V -> vT bf16 in-epilogue.
//  k_kv:      gload16-staged kt/vt, 1-chunk prefetch, 1 barrier/chunk,
//             fused norms; per-split slices kvp/pksump (no atomics).
//  k_red2:    kvt[bh][80][264] bf16 = transpose(sum_s kvp) + pksum row 64.
//  k_out:     kvl DMA-staged, fused norms; out = (pq@kv)/(pq@pksum+1e-6).

typedef _Float16 half8 __attribute__((ext_vector_type(8)));
typedef short short8 __attribute__((ext_vector_type(8)));
typedef float f32x4 __attribute__((ext_vector_type(4)));
typedef unsigned short ushort4v __attribute__((ext_vector_type(4)));
typedef unsigned short ushort_t;
typedef unsigned int uint_t;

#define QKV_LD 2048
#define KVT_ROW 264
#define KVT_SZ 21120  // 80*264 elems per bh

__device__ __forceinline__ ushort_t f2bf(float f) {
  uint_t u = __builtin_bit_cast(uint_t, f);
  u += 0x7fffu + ((u >> 16) & 1u);
  return (ushort_t)(u >> 16);
}

__device__ __forceinline__ void gload16(const void* g, void* l) {
  __builtin_amdgcn_global_load_lds(
      (const __attribute__((address_space(1))) void*)g,
      (__attribute__((address_space(3))) void*)l, 16, 0, 0);
}

#define ENTRY_BAR                                                  \
  asm volatile("s_waitcnt vmcnt(0) lgkmcnt(0)" ::: "memory");      \
  asm volatile("s_barrier" ::: "memory")
#define MID_BAR                                                    \
  asm volatile("s_waitcnt lgkmcnt(0)" ::: "memory");               \
  asm volatile("s_barrier" ::: "memory")

// ---------------- W transpose + omega convert + x convert (one launch) ----------------
__global__ void k_wtrans(const float* __restrict__ Wq, const float* __restrict__ Wk,
                         const float* __restrict__ Wv, const float* __restrict__ omega,
                         const float* __restrict__ x, _Float16* __restrict__ wt,
                         _Float16* __restrict__ om, _Float16* __restrict__ xh) {
  const int g = blockIdx.z;
  const int tx = threadIdx.x, ty = threadIdx.y;
  if (g >= 4) {
    size_t base = (((size_t)(g - 4) * 1024 + blockIdx.y * 32 + blockIdx.x) * 256 +
                   ty * 32 + tx) * 8;
    float4 f0 = *(const float4*)(x + base);
    float4 f1 = *(const float4*)(x + base + 4);
    half8 h;
    h[0] = (_Float16)f0.x; h[1] = (_Float16)f0.y; h[2] = (_Float16)f0.z; h[3] = (_Float16)f0.w;
    h[4] = (_Float16)f1.x; h[5] = (_Float16)f1.y; h[6] = (_Float16)f1.z; h[7] = (_Float16)f1.w;
    *(half8*)(xh + base) = h;
    return;
  }
  if (g == 3) {
    int idx = blockIdx.y * 32 + blockIdx.x;
    if (idx < 64) {
      int i = idx * 256 + ty * 32 + tx;
      om[i] = (_Float16)omega[i];
    }
    return;
  }
  __shared__ float t[32][33];
  const float* W = (g == 0) ? Wq : ((g == 1) ? Wk : Wv);
  const int n0 = blockIdx.x * 32, k0 = blockIdx.y * 32;
#pragma unroll
  for (int j = 0; j < 4; ++j)
    t[ty + j * 8][tx] = W[(size_t)(k0 + ty + j * 8) * 1024 + n0 + tx];
  __syncthreads();
  _Float16* o = wt + (size_t)g * 1024 * 1024;
#pragma unroll
  for (int j = 0; j < 4; ++j)
    o[(size_t)(n0 + ty + j * 8) * 1024 + k0 + tx] = (_Float16)t[tx][ty + j * 8];
}

// ---------------- QKV GEMM: 256x256, BK=32, ring-4, depth-3 prefetch ----------------
__global__ __launch_bounds__(512, 2) void k_gemm(const _Float16* __restrict__ xh,
                                                 const _Float16* __restrict__ wt,
                                                 ushort_t* __restrict__ qkv,
                                                 ushort_t* __restrict__ vT) {
  __shared__ _Float16 As[4][8192];  // 64 KB; T (36 KB) aliases As in epilogue
  __shared__ _Float16 Bs[4][8192];  // 64 KB
  const int vb = (blockIdx.x & 7) * 96 + (blockIdx.x >> 3);
  const int ct = vb % 12, rt = vb / 12;
  const int col0 = ct * 256, row0 = rt * 256;
  const int g = col0 >> 10;  // 0=Q 1=K 2=V
  const int col0g = col0 & 1023;
  const _Float16* wtg = wt + (size_t)g * (1024 * 1024);
  const int tid = threadIdx.x;
  const int lane = tid & 63;
  const int w = tid >> 6;
  const int wm = w >> 2, wn = w & 3;
  const int l15 = lane & 15, l4 = lane >> 4;

  int srow[2], scol[2], dst[2];
#pragma unroll
  for (int i = 0; i < 2; ++i) {
    int u = i * 512 + tid;
    int rb = u >> 6, rr = (u >> 2) & 15, ccb = u & 3;
    srow[i] = rb * 16 + rr;
    scol[i] = (ccb * 8) ^ ((rr & 8) ? 16 : 0);
    dst[i] = u * 8;
  }
  const int kx = (l4 * 8) ^ ((l15 & 8) ? 16 : 0);

  auto stageA = [&](int b, int kt) {
#pragma unroll
    for (int i = 0; i < 2; ++i)
      gload16(xh + (size_t)(row0 + srow[i]) * 1024 + kt * 32 + scol[i], &As[b][dst[i]]);
  };
  auto stageB = [&](int b, int kt) {
#pragma unroll
    for (int i = 0; i < 2; ++i)
      gload16(wtg + (size_t)(col0g + srow[i]) * 1024 + kt * 32 + scol[i], &Bs[b][dst[i]]);
  };

  f32x4 acc[8][4] = {};

  // prologue: tiles 0,1,2 fully staged (12 loads/thread in FIFO)
  stageA(0, 0); stageB(0, 0);
  stageA(1, 1); stageB(1, 1);
  stageA(2, 2); stageB(2, 2);

  for (int kt = 0; kt < 32; ++kt) {
    const int b = kt & 3, b3 = (kt + 3) & 3;
    // entry wait: retire exactly tile kt's A,B (issued 3 iters ago); keep 8 in flight
    if (kt < 30)       asm volatile("s_waitcnt vmcnt(8)" ::: "memory");
    else if (kt == 30) asm volatile("s_waitcnt vmcnt(4)" ::: "memory");
    else               asm volatile("s_waitcnt vmcnt(0)" ::: "memory");
    asm volatile("s_barrier" ::: "memory");
    // stage t+3 into buf (kt-1)&3 — safe: all waves' kt-1 reads done pre-barrier
    if (kt < 29) stageA(b3, kt + 3);

    const _Float16* Ab = &As[b][0];
    const _Float16* Bb = &Bs[b][0];
    half8 av[4], bv[4];
#pragma unroll
    for (int mi = 0; mi < 4; ++mi)
      av[mi] = *(const half8*)&Ab[(wm * 8 + mi) * 512 + l15 * 32 + kx];
#pragma unroll
    for (int ni = 0; ni < 4; ++ni)
      bv[ni] = *(const half8*)&Bb[(wn * 4 + ni) * 512 + l15 * 32 + kx];
    if (kt < 29) stageB(b3, kt + 3);
    __builtin_amdgcn_s_setprio(1);
#pragma unroll
    for (int mi = 0; mi < 4; ++mi)
#pragma unroll
      for (int ni = 0; ni < 4; ++ni)
        acc[mi][ni] = __builtin_amdgcn_mfma_f32_16x16x32_f16(av[mi], bv[ni], acc[mi][ni], 0, 0, 0);
    __builtin_amdgcn_s_setprio(0);

    half8 av2[4];
#pragma unroll
    for (int mi = 0; mi < 4; ++mi)
      av2[mi] = *(const half8*)&Ab[(wm * 8 + 4 + mi) * 512 + l15 * 32 + kx];
    __builtin_amdgcn_s_setprio(1);
#pragma unroll
    for (int mi = 0; mi < 4; ++mi)
#pragma unroll
      for (int ni = 0; ni < 4; ++ni)
        acc[4 + mi][ni] = __builtin_amdgcn_mfma_f32_16x16x32_f16(av2[mi], bv[ni], acc[4 + mi][ni], 0, 0, 0);
    __builtin_amdgcn_s_setprio(0);
  }

  if (g < 2) {
#pragma unroll
    for (int mi = 0; mi < 8; ++mi) {
      int gr0 = row0 + wm * 128 + mi * 16 + l4 * 4;
#pragma unroll
      for (int ni = 0; ni < 4; ++ni) {
        int gc = col0 + wn * 64 + ni * 16 + l15;
#pragma unroll
        for (int r = 0; r < 4; ++r)
          qkv[(size_t)(gr0 + r) * QKV_LD + gc] =
              __builtin_bit_cast(ushort_t, (_Float16)acc[mi][ni][r]);
      }
    }
  } else {
    ushort_t(*T)[72] = reinterpret_cast<ushort_t(*)[72]>(&As[0][0]);
    const int b_ = row0 >> 12;
    const int n0_ = row0 & 4095;
#pragma unroll
    for (int p = 0; p < 4; ++p) {
      __syncthreads();
      if (wm == (p >> 1)) {
        const int mi0 = (p & 1) * 4;
#pragma unroll
        for (int mi4 = 0; mi4 < 4; ++mi4) {
#pragma unroll
          for (int ni = 0; ni < 4; ++ni) {
            int c = wn * 64 + ni * 16 + l15;
            ushort4v tv;
#pragma unroll
            for (int r = 0; r < 4; ++r) tv[r] = f2bf(acc[mi0 + mi4][ni][r]);
            *(ushort4v*)&T[c][mi4 * 16 + l4 * 4] = tv;
          }
        }
      }
      __syncthreads();
#pragma unroll
      for (int i = 0; i < 4; ++i) {
        int u = i * 512 + tid;
        int c = u >> 3, nc = (u & 7) * 8;
        int h = (col0g + c) >> 6, d = c & 63;
        short8 v = *(const short8*)&T[c][nc];
        *(short8*)(vT + ((size_t)((b_ * 16 + h) * 64 + d)) * 4096 + n0_ + p * 64 + nc) = v;
      }
    }
  }
}

// ---------------- fused phi(k) + kv: 1 barrier/chunk, fused norms, no atomics ----------------
__global__ __launch_bounds__(256) void k_kv(const ushort_t* __restrict__ qkv,
                                            const ushort_t* __restrict__ vT,
                                            const _Float16* __restrict__ om,
                                            float* __restrict__ kvp,
                                            float* __restrict__ pksump) {
  __shared__ _Float16 kt2[2][4096];  // 8 KB each
  __shared__ ushort_t vt2[2][4096];
  __shared__ ushort_t pk[256][72];   // [m][n], wave-private per m-range
  const int bh = blockIdx.x, split = blockIdx.y;
  const int b = bh >> 4, h = bh & 15;
  const int tid = threadIdx.x, lane = tid & 63, w = tid >> 6;
  const int l15 = lane & 15, l4 = lane >> 4;

  int srow[2], scol[2], sdst[2];
#pragma unroll
  for (int i = 0; i < 2; ++i) {
    int u = i * 256 + tid;
    srow[i] = u >> 3;
    scol[i] = ((u & 7) ^ (srow[i] & 7)) * 8;
    sdst[i] = u * 8;
  }
  auto stage = [&](int buf, int c) {
    const int nbase = split * 512 + c * 64;
#pragma unroll
    for (int i = 0; i < 2; ++i) {
      gload16(qkv + (size_t)(b * 4096 + nbase + srow[i]) * QKV_LD + 1024 + h * 64 + scol[i],
              &kt2[buf][sdst[i]]);
      gload16(vT + (size_t)(bh * 64 + srow[i]) * 4096 + nbase + scol[i], &vt2[buf][sdst[i]]);
    }
  };

  half8 bom[4][2];
#pragma unroll
  for (int mf = 0; mf < 4; ++mf)
#pragma unroll
    for (int ks = 0; ks < 2; ++ks)
      bom[mf][ks] = *(const half8*)(om + (size_t)(w * 64 + mf * 16 + l15) * 64 + ks * 32 + l4 * 8);

  f32x4 kvacc[4][4] = {};
  float psum[4] = {0.f, 0.f, 0.f, 0.f};

  stage(0, 0);
#pragma unroll 1
  for (int c = 0; c < 8; ++c) {
    const int cb = c & 1;
    ENTRY_BAR;
    if (c < 7) stage(cb ^ 1, c + 1);
#pragma unroll
    for (int nf = 0; nf < 4; ++nf) {
      int arow = nf * 16 + l15;
      const _Float16* base = &kt2[cb][arow * 64];
      half8 a0 = *(const half8*)&base[(l4 ^ (arow & 7)) * 8];
      half8 a1 = *(const half8*)&base[((4 + l4) ^ (arow & 7)) * 8];
      float pn = 0.f;
#pragma unroll
      for (int e = 0; e < 8; ++e) {
        float u0 = (float)a0[e], u1 = (float)a1[e];
        pn += u0 * u0 + u1 * u1;
      }
      pn += __shfl_xor(pn, 16);
      pn += __shfl_xor(pn, 32);
      float nrr[4];
#pragma unroll
      for (int r = 0; r < 4; ++r) nrr[r] = __shfl(pn, l4 * 4 + r);
#pragma unroll
      for (int mf = 0; mf < 4; ++mf) {
        f32x4 f = {};
        f = __builtin_amdgcn_mfma_f32_16x16x32_f16(a0, bom[mf][0], f, 0, 0, 0);
        f = __builtin_amdgcn_mfma_f32_16x16x32_f16(a1, bom[mf][1], f, 0, 0, 0);
        ushort4v pw;
#pragma unroll
        for (int r = 0; r < 4; ++r) {
          float p = __expf(f[r] - 0.5f * nrr[r]) * 0.0625f;
          psum[mf] += p;
          pw[r] = f2bf(p);
        }
        *(ushort4v*)&pk[w * 64 + mf * 16 + l15][nf * 16 + l4 * 4] = pw;
      }
    }
#pragma unroll
    for (int ks = 0; ks < 2; ++ks) {
      short8 pa[4];
#pragma unroll
      for (int mf = 0; mf < 4; ++mf)
        pa[mf] = *(const short8*)&pk[w * 64 + mf * 16 + l15][ks * 32 + l4 * 8];
#pragma unroll
      for (int df = 0; df < 4; ++df) {
        int vrow = df * 16 + l15;
        short8 bv = *(const short8*)&vt2[cb][vrow * 64 + ((4 * ks + l4) ^ (vrow & 7)) * 8];
#pragma unroll
        for (int mf = 0; mf < 4; ++mf)
          kvacc[mf][df] = __builtin_amdgcn_mfma_f32_16x16x32_bf16(pa[mf], bv, kvacc[mf][df], 0, 0, 0);
      }
    }
  }
  float* slice = kvp + (size_t)(split * 64 + bh) * 16384;
#pragma unroll
  for (int mf = 0; mf < 4; ++mf)
#pragma unroll
    for (int df = 0; df < 4; ++df)
#pragma unroll
      for (int r = 0; r < 4; ++r) {
        int m = w * 64 + mf * 16 + l4 * 4 + r;
        int d = df * 16 + l15;
        slice[m * 64 + d] = kvacc[mf][df][r];
      }
#pragma unroll
  for (int mf = 0; mf < 4; ++mf) {
    float v = psum[mf];
    v += __shfl_xor(v, 16);
    v += __shfl_xor(v, 32);
    if (lane < 16)
      pksump[(size_t)(split * 64 + bh) * 256 + w * 64 + mf * 16 + lane] = v;
  }
}

// ---------------- reduce + transpose: kvt[bh][80][264] bf16 ----------------
__global__ __launch_bounds__(256) void k_red2(const float* __restrict__ kvp,
                                              const float* __restrict__ pksump,
                                              ushort_t* __restrict__ kvt) {
  __shared__ float kl[256][17];
  const int bh = blockIdx.x, jq = blockIdx.y, tid = threadIdx.x;
  const int d0 = jq * 16;
#pragma unroll
  for (int i = 0; i < 4; ++i) {
    int u = i * 256 + tid;
    int m = u >> 2, s = u & 3;
    f32x4 a = {};
#pragma unroll
    for (int sp = 0; sp < 8; ++sp)
      a += *(const f32x4*)(kvp + (size_t)(sp * 64 + bh) * 16384 + m * 64 + d0 + s * 4);
    *(f32x4*)&kl[m][s * 4] = a;
  }
  __syncthreads();
  const int mg = tid >> 4, jl = tid & 15;
  ushort_t* dstr = kvt + (size_t)bh * KVT_SZ + (d0 + jl) * KVT_ROW + mg * 16;
#pragma unroll
  for (int gpk = 0; gpk < 2; ++gpk) {
    short8 pack;
#pragma unroll
    for (int e = 0; e < 8; ++e)
      pack[e] = (short)f2bf(kl[mg * 16 + gpk * 8 + e][jl]);
    *(short8*)&dstr[gpk * 8] = pack;
  }
  if (jq == 0) {
    float s = 0.f;
#pragma unroll
    for (int sp = 0; sp < 8; ++sp) s += pksump[(size_t)(sp * 64 + bh) * 256 + tid];
    kvt[(size_t)bh * KVT_SZ + 64 * KVT_ROW + tid] = f2bf(s);
  }
  for (int idx = jq * 256 + tid; idx < 15 * KVT_ROW; idx += 1024)
    kvt[(size_t)bh * KVT_SZ + 65 * KVT_ROW + idx] = 0;
}

// ---------------- fused phi(q) + out: DMA-staged kvl, fused norms ----------------
__global__ __launch_bounds__(512) void k_out(const ushort_t* __restrict__ qkv,
                                             const ushort_t* __restrict__ kvt,
                                             const _Float16* __restrict__ om,
                                             float* __restrict__ outp) {
  __shared__ ushort_t kvl[80][KVT_ROW];
  __shared__ _Float16 qt2[2][8192];
  __shared__ ushort_t pq[128][264];
  const int bh = blockIdx.x, ns = blockIdx.y;
  const int b = bh >> 4, h = bh & 15;
  const int tid = threadIdx.x, lane = tid & 63, w = tid >> 6;
  const int l15 = lane & 15, l4 = lane >> 4;
  const int wn = w >> 2, wm = w & 3;

  {
    const ushort_t* kvsrc = kvt + (size_t)bh * KVT_SZ;
    ushort_t* dstl = &kvl[0][0];
#pragma unroll
    for (int i = 0; i < 6; ++i) {
      int u = i * 512 + tid;
      if (u < 2640) gload16(kvsrc + u * 8, dstl + u * 8);
    }
  }
  int srow[2], scol[2], sdst[2];
#pragma unroll
  for (int i = 0; i < 2; ++i) {
    int u = i * 512 + tid;
    srow[i] = u >> 3;
    scol[i] = ((u & 7) ^ (srow[i] & 7)) * 8;
    sdst[i] = u * 8;
  }
  auto stageQ = [&](int buf, int ch) {
    const int n0 = ns * 512 + ch * 128;
#pragma unroll
    for (int i = 0; i < 2; ++i)
      gload16((const _Float16*)qkv + (size_t)(b * 4096 + n0 + srow[i]) * QKV_LD + h * 64 + scol[i],
              &qt2[buf][sdst[i]]);
  };
  stageQ(0, 0);

  half8 bom[4][2];
#pragma unroll
  for (int mf = 0; mf < 4; ++mf)
#pragma unroll
    for (int ks = 0; ks < 2; ++ks)
      bom[mf][ks] = *(const half8*)(om + (size_t)(wm * 64 + mf * 16 + l15) * 64 + ks * 32 + l4 * 8);

#pragma unroll 1
  for (int ch = 0; ch < 4; ++ch) {
    const int cb = ch & 1;
    const int n0 = ns * 512 + ch * 128;
    ENTRY_BAR;
    if (ch < 3) stageQ(cb ^ 1, ch + 1);
#pragma unroll
    for (int nf = 0; nf < 4; ++nf) {
      int arow = wn * 64 + nf * 16 + l15;
      const _Float16* base = &qt2[cb][arow * 64];
      half8 qa0 = *(const half8*)&base[(l4 ^ (arow & 7)) * 8];
      half8 qa1 = *(const half8*)&base[((4 + l4) ^ (arow & 7)) * 8];
      float pn = 0.f;
#pragma unroll
      for (int e = 0; e < 8; ++e) {
        float u0 = (float)qa0[e], u1 = (float)qa1[e];
        pn += u0 * u0 + u1 * u1;
      }
      pn += __shfl_xor(pn, 16);
      pn += __shfl_xor(pn, 32);
      float nr = 0.5f * pn;
#pragma unroll
      for (int mf = 0; mf < 4; ++mf) {
        f32x4 f = {};
        f = __builtin_amdgcn_mfma_f32_16x16x32_f16(bom[mf][0], qa0, f, 0, 0, 0);
        f = __builtin_amdgcn_mfma_f32_16x16x32_f16(bom[mf][1], qa1, f, 0, 0, 0);
        ushort4v pw;
#pragma unroll
        for (int r = 0; r < 4; ++r) {
          float p = __expf(f[r] - nr) * 0.0625f;
          pw[r] = f2bf(p);
        }
        *(ushort4v*)&pq[wn * 64 + nf * 16 + l15][wm * 64 + mf * 16 + l4 * 4] = pw;
      }
    }
    MID_BAR;
    f32x4 oacc[5] = {};
#pragma unroll
    for (int ks = 0; ks < 8; ++ks) {
      short8 pa = *(const short8*)&pq[w * 16 + l15][ks * 32 + l4 * 8];
#pragma unroll
      for (int cf = 0; cf < 5; ++cf) {
        short8 bv = *(const short8*)&kvl[cf * 16 + l15][ks * 32 + l4 * 8];
        oacc[cf] = __builtin_amdgcn_mfma_f32_16x16x32_bf16(pa, bv, oacc[cf], 0, 0, 0);
      }
    }
#pragma unroll
    for (int r = 0; r < 4; ++r) {
      float z = __shfl(oacc[4][r], lane & 48);
      float inv = 1.0f / (z + 1e-6f);
      int n = n0 + w * 16 + l4 * 4 + r;
#pragma unroll
      for (int cf = 0; cf < 4; ++cf)
        outp[(size_t)(b * 4096 + n) * 1024 + h * 64 + cf * 16 + l15] = oacc[cf][r] * inv;
    }
  }
}

extern "C" void kernel_launch(void* const* d_in, const int* in_sizes, int n_in,
                              void* d_out, int out_size, void* d_ws, size_t ws_size,
                              hipStream_t stream) {
  const float* x = (const float*)d_in[0];
  const float* Wq = (const float*)d_in[1];
  const float* Wk = (const float*)d_in[2];
  const float* Wv = (const float*)d_in[3];
  const float* omg = (const float*)d_in[4];
  float* outp = (float*)d_out;
  char* ws = (char*)d_ws;

  _Float16* wt = (_Float16*)(ws);                 // 6,291,456 (dead after gemm)
  ushort_t* kvt = (ushort_t*)(ws);                // 2,703,360 (aliases wt)
  _Float16* om = (_Float16*)(ws + 6291456);       //    32,768
  ushort_t* qkv = (ushort_t*)(ws + 6324224);      // 67,108,864 (Q|K, stride 2048)
  ushort_t* vT = (ushort_t*)(ws + 73433088);      // 33,554,432
  _Float16* xh = (_Float16*)(ws + 106987520);     // 33,554,432 (dead after gemm)
  float* kvp = (float*)(ws + 106987520);          // 33,554,432 (aliases xh)
  float* pksump = (float*)(ws + 140541952);       //    524,288

  k_wtrans<<<dim3(32, 32, 12), dim3(32, 8), 0, stream>>>(Wq, Wk, Wv, omg, x, wt, om, xh);
  k_gemm<<<dim3(768), dim3(512), 0, stream>>>(xh, wt, qkv, vT);
  k_kv<<<dim3(64, 8), dim3(256), 0, stream>>>(qkv, vT, om, kvp, pksump);
  k_red2<<<dim3(64, 4), dim3(256), 0, stream>>>(kvp, pksump, kvt);
  k_out<<<dim3(64, 8), dim3(512), 0, stream>>>(qkv, kvt, om, outp);
}